// Round 7
// baseline (281.442 us; speedup 1.0000x reference)
//
#include <hip/hip_runtime.h>
#include <math.h>

typedef short bf16x8 __attribute__((ext_vector_type(8)));   // 8 bf16 in 4 VGPRs
typedef float f32x4  __attribute__((ext_vector_type(4)));

#define TPB 256
#define WROWS 64          // rows per WAVE-chunk (the work unit is now a wave)
#define CSTRIDE 36        // Ct row stride (floats)
#define BFR_BYTES 16384   // 2 ntiles x 4 ksteps x 2 planes x 64 lanes x 16B
#define CT_BYTES (256 * CSTRIDE * 4)      // 4 waves x 64 rows x CSTRIDE
#define PK(lo, hi) (((lo) >> 16) | ((hi) & 0xffff0000u))
#define BOFF(nt, ks, p) ((((nt)*4 + (ks))*2 + (p))*256)
#define GRID 768          // 3 blocks/CU; 12 independent wave-pipelines per CU

// 2-plane split: p1 = RNE-bf16(x), p2 = trunc-bf16(x - p1); 3 of 4 cross terms kept
__device__ __forceinline__ void split2A(float x, unsigned &h1, unsigned &h2) {
    unsigned u = __float_as_uint(x);
    h1 = (u + 0x7fffu + ((u >> 16) & 1u)) & 0xffff0000u;
    h2 = __float_as_uint(x - __uint_as_float(h1));   // PK takes high 16 bits
}
__device__ __forceinline__ void split2W(float x, unsigned &h1, unsigned &h2) {
    unsigned u = __float_as_uint(x);
    h1 = (u + 0x7fffu + ((u >> 16) & 1u)) & 0xffff0000u;
    float r1 = x - __uint_as_float(h1);
    unsigned u1 = __float_as_uint(r1);
    h2 = (u1 + 0x7fffu + ((u1 >> 16) & 1u)) & 0xffff0000u;
}

__global__ __launch_bounds__(TPB, 3) void decoder_kernel(
    const float* __restrict__ feat,
    const float* __restrict__ W1, const float* __restrict__ g1, const float* __restrict__ b1,
    const float* __restrict__ W2, const float* __restrict__ g2, const float* __restrict__ b2,
    const float* __restrict__ W3, const float* __restrict__ b3,
    float* __restrict__ out, int N,
    unsigned* __restrict__ ctr, unsigned nchunks)
{
    __shared__ __align__(16) unsigned char lds[BFR_BYTES + CT_BYTES];  // 53248 B -> 3/CU
    unsigned* bfr = (unsigned*)lds;

    const int t = threadIdx.x;
    const int l = t & 63;
    const int w = t >> 6;
    const int arow = l & 15;        // A-fragment: m = l&15
    const int acol = (l >> 4) * 8;  //             k-base = (l>>4)*8
    float* myCt = (float*)(lds + BFR_BYTES) + w * WROWS * CSTRIDE;  // wave-private slice

    // ---------------- prologue (once): W1 -> 2-plane bf16 B-fragments --------
    for (int c = t; c < 512; c += 256) {
        const int lc = c & 63, ks = (c >> 6) & 3, nt = (c >> 8) & 1;
        const float* wp = W1 + (nt * 16 + (lc & 15)) * 128 + ks * 32 + (lc >> 4) * 8;
        float v[8];
        *(float4*)(v)     = *(const float4*)(wp);
        *(float4*)(v + 4) = *(const float4*)(wp + 4);
        unsigned h1[8], h2[8];
#pragma unroll
        for (int i = 0; i < 8; ++i) split2W(v[i], h1[i], h2[i]);
        uint4 q1 = {PK(h1[0],h1[1]), PK(h1[2],h1[3]), PK(h1[4],h1[5]), PK(h1[6],h1[7])};
        uint4 q2 = {PK(h2[0],h2[1]), PK(h2[2],h2[3]), PK(h2[4],h2[5]), PK(h2[6],h2[7])};
        *(uint4*)(bfr + BOFF(nt, ks, 0) + lc * 4) = q1;
        *(uint4*)(bfr + BOFF(nt, ks, 1) + lc * 4) = q2;
    }
    __syncthreads();   // the ONLY barrier; bfr is read-only hereafter

    // per-wave work grab: one atomic by lane 0, broadcast
    unsigned v0 = 0;
    if (l == 0) v0 = atomicAdd(ctr, 1u);
    unsigned cur = (unsigned)__builtin_amdgcn_readfirstlane((int)v0);

    float4 buf[2][8];
    if (cur < nchunks) {             // preload tile 0 of first chunk
        size_t rr = (size_t)cur * WROWS + arow;
        if (rr >= (size_t)N) rr = N - 1;
        const float* ap = feat + rr * 128 + acol;
#pragma unroll
        for (int ks = 0; ks < 4; ++ks) {
            buf[0][2 * ks]     = *(const float4*)(ap + ks * 32);
            buf[0][2 * ks + 1] = *(const float4*)(ap + ks * 32 + 4);
        }
    }

    while (cur < nchunks) {
        const size_t blk0 = (size_t)cur * WROWS;

        // grab NEXT chunk now; atomic latency hides under the whole chunk
        unsigned v1 = 0;
        if (l == 0) v1 = atomicAdd(ctr, 1u);
        const unsigned nxt = (unsigned)__builtin_amdgcn_readfirstlane((int)v1);

        // ---------------- layer 1 via MFMA: 4 row-tiles of 16 -----------------
#pragma unroll
        for (int j = 0; j < 4; ++j) {
            // prefetch: j<3 -> next tile of cur; j==3 -> tile 0 of nxt
            const bool pf_valid = (j < 3) | (nxt < nchunks);
            if (pf_valid) {
                const size_t pbase = (j < 3) ? (blk0 + (j + 1) * 16)
                                             : ((size_t)nxt * WROWS);
                size_t rr = pbase + arow;
                if (rr >= (size_t)N) rr = N - 1;
                const float* ap = feat + rr * 128 + acol;
#pragma unroll
                for (int ks = 0; ks < 4; ++ks) {
                    buf[(j + 1) & 1][2 * ks]     = *(const float4*)(ap + ks * 32);
                    buf[(j + 1) & 1][2 * ks + 1] = *(const float4*)(ap + ks * 32 + 4);
                }
            }
            f32x4 acc0 = {0.f, 0.f, 0.f, 0.f};
            f32x4 acc1 = {0.f, 0.f, 0.f, 0.f};
#pragma unroll
            for (int ks = 0; ks < 4; ++ks) {
                float v[8];
                *(float4*)(v)     = buf[j & 1][2 * ks];
                *(float4*)(v + 4) = buf[j & 1][2 * ks + 1];
                unsigned h1[8], h2[8];
#pragma unroll
                for (int i = 0; i < 8; ++i) split2A(v[i], h1[i], h2[i]);
                uint4 q1 = {PK(h1[0],h1[1]), PK(h1[2],h1[3]), PK(h1[4],h1[5]), PK(h1[6],h1[7])};
                uint4 q2 = {PK(h2[0],h2[1]), PK(h2[2],h2[3]), PK(h2[4],h2[5]), PK(h2[6],h2[7])};
                bf16x8 a1 = __builtin_bit_cast(bf16x8, q1);
                bf16x8 a2 = __builtin_bit_cast(bf16x8, q2);
                bf16x8 B10 = __builtin_bit_cast(bf16x8, *(const uint4*)(bfr + BOFF(0, ks, 0) + l * 4));
                bf16x8 B20 = __builtin_bit_cast(bf16x8, *(const uint4*)(bfr + BOFF(0, ks, 1) + l * 4));
                bf16x8 B11 = __builtin_bit_cast(bf16x8, *(const uint4*)(bfr + BOFF(1, ks, 0) + l * 4));
                bf16x8 B21 = __builtin_bit_cast(bf16x8, *(const uint4*)(bfr + BOFF(1, ks, 1) + l * 4));
                acc0 = __builtin_amdgcn_mfma_f32_16x16x32_bf16(a1, B10, acc0, 0, 0, 0);
                acc1 = __builtin_amdgcn_mfma_f32_16x16x32_bf16(a1, B11, acc1, 0, 0, 0);
                acc0 = __builtin_amdgcn_mfma_f32_16x16x32_bf16(a2, B10, acc0, 0, 0, 0);
                acc1 = __builtin_amdgcn_mfma_f32_16x16x32_bf16(a2, B11, acc1, 0, 0, 0);
                acc0 = __builtin_amdgcn_mfma_f32_16x16x32_bf16(a1, B20, acc0, 0, 0, 0);
                acc1 = __builtin_amdgcn_mfma_f32_16x16x32_bf16(a1, B21, acc1, 0, 0, 0);
            }
            // C/D layout: col = l&15, row = (l>>4)*4 + reg -> wave-private Ct slice
            const int crow = j * 16 + (l >> 4) * 4;
            const int ccol = l & 15;
#pragma unroll
            for (int r = 0; r < 4; ++r) {
                myCt[(crow + r) * CSTRIDE + ccol]      = acc0[r];
                myCt[(crow + r) * CSTRIDE + 16 + ccol] = acc1[r];
            }
        }

        // wave-coherent handoff: DS pipe is in-order per wave; compiler inserts
        // lgkmcnt waits for the read results. No barrier.
        float x[32];
#pragma unroll
        for (int c = 0; c < 8; ++c)
            *(float4*)(x + c * 4) = *(const float4*)(myCt + l * CSTRIDE + c * 4);

        // ---------------- tail: lane l owns row blk0 + l ----------------------
        float m = 0.f;
#pragma unroll
        for (int j = 0; j < 32; ++j) m += x[j];
        m *= (1.f / 32.f);
        float var = 0.f;
#pragma unroll
        for (int j = 0; j < 32; ++j) { const float d = x[j] - m; var = fmaf(d, d, var); }
        var *= (1.f / 32.f);
        const float rs1 = rsqrtf(var + 1e-5f);

        float z[32];
#pragma unroll
        for (int j = 0; j < 32; ++j) {
            float y = (x[j] - m) * rs1 * g1[j] + b1[j];
            z[j] = (y >= 0.f) ? y : 0.1f * y;
        }

        float a2v[16];
#pragma unroll
        for (int k = 0; k < 16; ++k) {
            const float* __restrict__ wrow = W2 + k * 32;
            float s = 0.f;
#pragma unroll
            for (int j = 0; j < 32; ++j) s = fmaf(z[j], wrow[j], s);
            a2v[k] = s;
        }

        float m2 = 0.f;
#pragma unroll
        for (int k = 0; k < 16; ++k) m2 += a2v[k];
        m2 *= (1.f / 16.f);
        float v2 = 0.f;
#pragma unroll
        for (int k = 0; k < 16; ++k) { const float d = a2v[k] - m2; v2 = fmaf(d, d, v2); }
        v2 *= (1.f / 16.f);
        const float rs2 = rsqrtf(v2 + 1e-5f);

        float z2[16];
#pragma unroll
        for (int k = 0; k < 16; ++k) {
            float y = (a2v[k] - m2) * rs2 * g2[k] + b2[k];
            z2[k] = (y >= 0.f) ? y : 0.1f * y;
        }

        float o[3];
#pragma unroll
        for (int q = 0; q < 3; ++q) {
            const float* __restrict__ wrow = W3 + q * 16;
            float s = b3[q];
#pragma unroll
            for (int k = 0; k < 16; ++k) s = fmaf(z2[k], wrow[k], s);
            o[q] = s;
        }
        const float nrm = sqrtf(o[0]*o[0] + o[1]*o[1] + o[2]*o[2]);
        const float inv = 1.f / fmaxf(nrm, 1e-12f);

        const size_t myrow = blk0 + l;
        if (myrow < (size_t)N) {
            out[myrow * 3 + 0] = o[0] * inv;
            out[myrow * 3 + 1] = o[1] * inv;
            out[myrow * 3 + 2] = o[2] * inv;
        }

        cur = nxt;
    }
}

extern "C" void kernel_launch(void* const* d_in, const int* in_sizes, int n_in,
                              void* d_out, int out_size, void* d_ws, size_t ws_size,
                              hipStream_t stream) {
    const float* feat = (const float*)d_in[0];
    const float* W1   = (const float*)d_in[1];
    const float* g1   = (const float*)d_in[2];
    const float* b1   = (const float*)d_in[3];
    const float* W2   = (const float*)d_in[4];
    const float* g2   = (const float*)d_in[5];
    const float* b2   = (const float*)d_in[6];
    const float* W3   = (const float*)d_in[7];
    const float* b3   = (const float*)d_in[8];
    float* out = (float*)d_out;

    const int N = in_sizes[0] / 128;
    const unsigned nchunks = (unsigned)((N + WROWS - 1) / WROWS);
    unsigned* ctr = (unsigned*)d_ws;

    hipMemsetAsync(ctr, 0, sizeof(unsigned), stream);   // stream-ordered, graph-safe
    decoder_kernel<<<GRID, TPB, 0, stream>>>(feat, W1, g1, b1, W2, g2, b2, W3, b3,
                                             out, N, ctr, nchunks);
}

// Round 8
// 125.338 us; speedup vs baseline: 2.2455x; 2.2455x over previous
//
#include <hip/hip_runtime.h>
#include <math.h>

typedef short bf16x8 __attribute__((ext_vector_type(8)));   // 8 bf16 in 4 VGPRs
typedef float f32x4  __attribute__((ext_vector_type(4)));

#define TPB 256
#define ROWS 256
#define CSTRIDE 36        // Ct row stride (floats): rows 16B-aligned
#define BFR_BYTES 16384   // 2 ntiles x 4 ksteps x 2 planes x 64 lanes x 16B
#define CT_BYTES (ROWS * CSTRIDE * 4)
#define BOFF(nt, ks, p) ((((nt)*4 + (ks))*2 + (p))*256)
#define GRID 768          // 3 blocks/CU x 256 CUs; persistent, block-level atomic queue

// lgkm-only barrier: LDS visibility without draining the global prefetch queue
#define WBAR() do { asm volatile("s_waitcnt lgkmcnt(0)" ::: "memory"); \
                    __builtin_amdgcn_s_barrier(); } while (0)

// v_cvt_pk_bf16_f32: RNE-round two f32 into one packed 2xbf16 word (1 instr)
__device__ __forceinline__ unsigned cvt_pk_bf16(float lo, float hi) {
    unsigned r;
    asm("v_cvt_pk_bf16_f32 %0, %1, %2" : "=v"(r) : "v"(lo), "v"(hi));
    return r;
}

// 2-plane split of a pair: p = RNE(x0),RNE(x1); q = RNE(residuals).
// |x - p - q| <= 2^-17 |x|; 3 of 4 cross products kept in the MFMA.
__device__ __forceinline__ void split2pk(float x0, float x1, unsigned &p, unsigned &q) {
    p = cvt_pk_bf16(x0, x1);
    const float f0 = __uint_as_float(p << 16);
    const float f1 = __uint_as_float(p & 0xffff0000u);
    q = cvt_pk_bf16(x0 - f0, x1 - f1);
}

__global__ __launch_bounds__(TPB, 3) void decoder_kernel(
    const float* __restrict__ feat,
    const float* __restrict__ W1, const float* __restrict__ g1, const float* __restrict__ b1,
    const float* __restrict__ W2, const float* __restrict__ g2, const float* __restrict__ b2,
    const float* __restrict__ W3, const float* __restrict__ b3,
    float* __restrict__ out, int N,
    unsigned* __restrict__ ctr, unsigned nchunks)
{
    __shared__ __align__(16) unsigned char lds[BFR_BYTES + CT_BYTES + 16];  // 53264 B -> 3/CU
    unsigned* bfr = (unsigned*)lds;
    float*    Ct  = (float*)(lds + BFR_BYTES);
    volatile unsigned* nxt_sh = (volatile unsigned*)(lds + BFR_BYTES + CT_BYTES);

    const int t = threadIdx.x;
    const int l = t & 63;
    const int w = t >> 6;
    const int arow = l & 15;        // A-fragment: m = l&15
    const int acol = (l >> 4) * 8;  //             k-base = (l>>4)*8

    // ---------------- prologue (ONCE per persistent block) -------------------
    for (int c = t; c < 512; c += 256) {
        const int lc = c & 63, ks = (c >> 6) & 3, nt = (c >> 8) & 1;
        const float* wp = W1 + (nt * 16 + (lc & 15)) * 128 + ks * 32 + (lc >> 4) * 8;
        float v[8];
        *(float4*)(v)     = *(const float4*)(wp);
        *(float4*)(v + 4) = *(const float4*)(wp + 4);
        unsigned p[4], q[4];
#pragma unroll
        for (int i = 0; i < 4; ++i) split2pk(v[2*i], v[2*i+1], p[i], q[i]);
        uint4 q1 = {p[0], p[1], p[2], p[3]};
        uint4 q2 = {q[0], q[1], q[2], q[3]};
        *(uint4*)(bfr + BOFF(nt, ks, 0) + lc * 4) = q1;
        *(uint4*)(bfr + BOFF(nt, ks, 1) + lc * 4) = q2;
    }
    if (t == 0) *nxt_sh = atomicAdd(ctr, 1u);
    __syncthreads();                 // bfr + first chunk id ready
    unsigned cur = *nxt_sh;

    float4 buf[2][8];
    if (cur < nchunks) {             // preload tile 0 of first chunk
        size_t rr = (size_t)cur * ROWS + (size_t)w * 64 + arow;
        if (rr >= (size_t)N) rr = N - 1;
        const float* ap = feat + rr * 128 + acol;
#pragma unroll
        for (int ks = 0; ks < 4; ++ks) {
            buf[0][2 * ks]     = *(const float4*)(ap + ks * 32);
            buf[0][2 * ks + 1] = *(const float4*)(ap + ks * 32 + 4);
        }
    }

    while (cur < nchunks) {
        const size_t blk0 = (size_t)cur * ROWS;

        // ---------------- layer 1 via MFMA: 4 row-tiles of 16 per wave ------
#pragma unroll
        for (int j = 0; j < 4; ++j) {
            if (j == 1 && t == 0) *nxt_sh = atomicAdd(ctr, 1u);  // grab next chunk early
            if (j < 3) {  // prefetch next row-tile
                size_t rr = blk0 + (size_t)w * 64 + (j + 1) * 16 + arow;
                if (rr >= (size_t)N) rr = N - 1;
                const float* ap = feat + rr * 128 + acol;
#pragma unroll
                for (int ks = 0; ks < 4; ++ks) {
                    buf[(j + 1) & 1][2 * ks]     = *(const float4*)(ap + ks * 32);
                    buf[(j + 1) & 1][2 * ks + 1] = *(const float4*)(ap + ks * 32 + 4);
                }
            }
            f32x4 acc0 = {0.f, 0.f, 0.f, 0.f};
            f32x4 acc1 = {0.f, 0.f, 0.f, 0.f};
#pragma unroll
            for (int ks = 0; ks < 4; ++ks) {
                float v[8];
                *(float4*)(v)     = buf[j & 1][2 * ks];
                *(float4*)(v + 4) = buf[j & 1][2 * ks + 1];
                unsigned p[4], q[4];
#pragma unroll
                for (int i = 0; i < 4; ++i) split2pk(v[2*i], v[2*i+1], p[i], q[i]);
                uint4 q1 = {p[0], p[1], p[2], p[3]};
                uint4 q2 = {q[0], q[1], q[2], q[3]};
                bf16x8 a1 = __builtin_bit_cast(bf16x8, q1);
                bf16x8 a2 = __builtin_bit_cast(bf16x8, q2);
                bf16x8 B10 = __builtin_bit_cast(bf16x8, *(const uint4*)(bfr + BOFF(0, ks, 0) + l * 4));
                bf16x8 B20 = __builtin_bit_cast(bf16x8, *(const uint4*)(bfr + BOFF(0, ks, 1) + l * 4));
                bf16x8 B11 = __builtin_bit_cast(bf16x8, *(const uint4*)(bfr + BOFF(1, ks, 0) + l * 4));
                bf16x8 B21 = __builtin_bit_cast(bf16x8, *(const uint4*)(bfr + BOFF(1, ks, 1) + l * 4));
                acc0 = __builtin_amdgcn_mfma_f32_16x16x32_bf16(a1, B10, acc0, 0, 0, 0);
                acc1 = __builtin_amdgcn_mfma_f32_16x16x32_bf16(a1, B11, acc1, 0, 0, 0);
                acc0 = __builtin_amdgcn_mfma_f32_16x16x32_bf16(a2, B10, acc0, 0, 0, 0);
                acc1 = __builtin_amdgcn_mfma_f32_16x16x32_bf16(a2, B11, acc1, 0, 0, 0);
                acc0 = __builtin_amdgcn_mfma_f32_16x16x32_bf16(a1, B20, acc0, 0, 0, 0);
                acc1 = __builtin_amdgcn_mfma_f32_16x16x32_bf16(a1, B21, acc1, 0, 0, 0);
            }
            // C/D layout: col = l&15, row = (l>>4)*4 + reg
            const int crow = w * 64 + j * 16 + (l >> 4) * 4;
            const int ccol = l & 15;
#pragma unroll
            for (int r = 0; r < 4; ++r) {
                Ct[(crow + r) * CSTRIDE + ccol]      = acc0[r];
                Ct[(crow + r) * CSTRIDE + 16 + ccol] = acc1[r];
            }
        }
        WBAR();   // Ct complete + nxt_sh visible (global prefetches stay in flight)

        float x[32];
#pragma unroll
        for (int c = 0; c < 8; ++c)
            *(float4*)(x + c * 4) = *(const float4*)(Ct + t * CSTRIDE + c * 4);
        const unsigned nxt = *nxt_sh;
        WBAR();   // all Ct reads retired; Ct may be overwritten next iteration

        if (nxt < nchunks) {   // next chunk's tile 0 flies under the tail
            size_t rr = (size_t)nxt * ROWS + (size_t)w * 64 + arow;
            if (rr >= (size_t)N) rr = N - 1;
            const float* ap = feat + rr * 128 + acol;
#pragma unroll
            for (int ks = 0; ks < 4; ++ks) {
                buf[0][2 * ks]     = *(const float4*)(ap + ks * 32);
                buf[0][2 * ks + 1] = *(const float4*)(ap + ks * 32 + 4);
            }
        }

        // ---------------- tail: thread t owns row blk0 + t --------------------
        float m = 0.f;
#pragma unroll
        for (int j = 0; j < 32; ++j) m += x[j];
        m *= (1.f / 32.f);
        float var = 0.f;
#pragma unroll
        for (int j = 0; j < 32; ++j) { const float d = x[j] - m; var = fmaf(d, d, var); }
        var *= (1.f / 32.f);
        const float rs1 = rsqrtf(var + 1e-5f);

        float z[32];
#pragma unroll
        for (int j = 0; j < 32; ++j) {
            float y = (x[j] - m) * rs1 * g1[j] + b1[j];
            z[j] = (y >= 0.f) ? y : 0.1f * y;
        }

        float a2v[16];
#pragma unroll
        for (int k = 0; k < 16; ++k) {
            const float* __restrict__ wrow = W2 + k * 32;
            float s = 0.f;
#pragma unroll
            for (int j = 0; j < 32; ++j) s = fmaf(z[j], wrow[j], s);
            a2v[k] = s;
        }

        float m2 = 0.f;
#pragma unroll
        for (int k = 0; k < 16; ++k) m2 += a2v[k];
        m2 *= (1.f / 16.f);
        float v2 = 0.f;
#pragma unroll
        for (int k = 0; k < 16; ++k) { const float d = a2v[k] - m2; v2 = fmaf(d, d, v2); }
        v2 *= (1.f / 16.f);
        const float rs2 = rsqrtf(v2 + 1e-5f);

        float z2[16];
#pragma unroll
        for (int k = 0; k < 16; ++k) {
            float y = (a2v[k] - m2) * rs2 * g2[k] + b2[k];
            z2[k] = (y >= 0.f) ? y : 0.1f * y;
        }

        float o[3];
#pragma unroll
        for (int q = 0; q < 3; ++q) {
            const float* __restrict__ wrow = W3 + q * 16;
            float s = b3[q];
#pragma unroll
            for (int k = 0; k < 16; ++k) s = fmaf(z2[k], wrow[k], s);
            o[q] = s;
        }
        const float nrm = sqrtf(o[0]*o[0] + o[1]*o[1] + o[2]*o[2]);
        const float inv = 1.f / fmaxf(nrm, 1e-12f);

        const size_t myrow = blk0 + t;
        if (myrow < (size_t)N) {
            out[myrow * 3 + 0] = o[0] * inv;
            out[myrow * 3 + 1] = o[1] * inv;
            out[myrow * 3 + 2] = o[2] * inv;
        }

        cur = nxt;
    }
}

extern "C" void kernel_launch(void* const* d_in, const int* in_sizes, int n_in,
                              void* d_out, int out_size, void* d_ws, size_t ws_size,
                              hipStream_t stream) {
    const float* feat = (const float*)d_in[0];
    const float* W1   = (const float*)d_in[1];
    const float* g1   = (const float*)d_in[2];
    const float* b1   = (const float*)d_in[3];
    const float* W2   = (const float*)d_in[4];
    const float* g2   = (const float*)d_in[5];
    const float* b2   = (const float*)d_in[6];
    const float* W3   = (const float*)d_in[7];
    const float* b3   = (const float*)d_in[8];
    float* out = (float*)d_out;

    const int N = in_sizes[0] / 128;
    const unsigned nchunks = (unsigned)((N + ROWS - 1) / ROWS);
    unsigned* ctr = (unsigned*)d_ws;

    hipMemsetAsync(ctr, 0, sizeof(unsigned), stream);   // stream-ordered, graph-safe
    decoder_kernel<<<GRID, TPB, 0, stream>>>(feat, W1, g1, b1, W2, g2, b2, W3, b3,
                                             out, N, ctr, nchunks);
}

// Round 9
// 120.664 us; speedup vs baseline: 2.3324x; 1.0387x over previous
//
#include <hip/hip_runtime.h>
#include <math.h>

typedef short bf16x8 __attribute__((ext_vector_type(8)));   // 8 bf16 in 4 VGPRs
typedef float f32x4  __attribute__((ext_vector_type(4)));

#define TPB 256
#define CSTRIDE 36        // Ct row stride (floats): rows 16B-aligned
#define BFR_BYTES 16384   // 2 ntiles x 4 ksteps x 2 planes x 64 lanes x 16B
#define CT_BYTES (256 * CSTRIDE * 4)      // 4 waves x 64 rows
#define BOFF(nt, ks, p) ((((nt)*4 + (ks))*2 + (p))*256)

// v_cvt_pk_bf16_f32: RNE-round two f32 into one packed 2xbf16 word
__device__ __forceinline__ unsigned cvt_pk_bf16(float lo, float hi) {
    unsigned r;
    asm("v_cvt_pk_bf16_f32 %0, %1, %2" : "=v"(r) : "v"(lo), "v"(hi));
    return r;
}
// 2-plane split of a pair: p = RNE(x0),RNE(x1); q = RNE(residuals).
__device__ __forceinline__ void split2pk(float x0, float x1, unsigned &p, unsigned &q) {
    p = cvt_pk_bf16(x0, x1);
    const float f0 = __uint_as_float(p << 16);
    const float f1 = __uint_as_float(p & 0xffff0000u);
    q = cvt_pk_bf16(x0 - f0, x1 - f1);
}

__global__ __launch_bounds__(TPB, 3) void decoder_kernel(
    const float* __restrict__ feat,
    const float* __restrict__ W1, const float* __restrict__ g1, const float* __restrict__ b1,
    const float* __restrict__ W2, const float* __restrict__ g2, const float* __restrict__ b2,
    const float* __restrict__ W3, const float* __restrict__ b3,
    float* __restrict__ out, int N)
{
    __shared__ __align__(16) unsigned char lds[BFR_BYTES + CT_BYTES];  // 53248 B -> 3/CU
    unsigned* bfr = (unsigned*)lds;

    const int t = threadIdx.x;
    const int l = t & 63;
    const int w = t >> 6;
    const int arow = l & 15;        // A-fragment: m = l&15
    const int acol = (l >> 4) * 8;  //             k-base = (l>>4)*8
    float* myCt = (float*)(lds + BFR_BYTES) + w * 64 * CSTRIDE;  // wave-private slice

    const size_t rows0 = (size_t)blockIdx.x * 256 + (size_t)w * 64;  // this wave's 64 rows

    // issue tile-0 loads FIRST; they fly under the prologue + barrier
    float4 buf[2][8];
    {
        size_t rr = rows0 + arow;
        if (rr >= (size_t)N) rr = N - 1;
        const float* ap = feat + rr * 128 + acol;
#pragma unroll
        for (int ks = 0; ks < 4; ++ks) {
            buf[0][2 * ks]     = *(const float4*)(ap + ks * 32);
            buf[0][2 * ks + 1] = *(const float4*)(ap + ks * 32 + 4);
        }
    }

    // ---------------- prologue: W1 -> 2-plane bf16 B-fragments in LDS --------
    for (int c = t; c < 512; c += 256) {
        const int lc = c & 63, ks = (c >> 6) & 3, nt = (c >> 8) & 1;
        const float* wp = W1 + (nt * 16 + (lc & 15)) * 128 + ks * 32 + (lc >> 4) * 8;
        float v[8];
        *(float4*)(v)     = *(const float4*)(wp);
        *(float4*)(v + 4) = *(const float4*)(wp + 4);
        unsigned p[4], q[4];
#pragma unroll
        for (int i = 0; i < 4; ++i) split2pk(v[2*i], v[2*i+1], p[i], q[i]);
        uint4 q1 = {p[0], p[1], p[2], p[3]};
        uint4 q2 = {q[0], q[1], q[2], q[3]};
        *(uint4*)(bfr + BOFF(nt, ks, 0) + lc * 4) = q1;
        *(uint4*)(bfr + BOFF(nt, ks, 1) + lc * 4) = q2;
    }
    __syncthreads();   // the ONLY barrier; bfr is read-only hereafter, waves free-run

    // ---------------- layer 1 via MFMA: 4 row-tiles of 16, wave-private ------
#pragma unroll
    for (int j = 0; j < 4; ++j) {
        if (j < 3) {   // prefetch next row-tile
            size_t rr = rows0 + (j + 1) * 16 + arow;
            if (rr >= (size_t)N) rr = N - 1;
            const float* ap = feat + rr * 128 + acol;
#pragma unroll
            for (int ks = 0; ks < 4; ++ks) {
                buf[(j + 1) & 1][2 * ks]     = *(const float4*)(ap + ks * 32);
                buf[(j + 1) & 1][2 * ks + 1] = *(const float4*)(ap + ks * 32 + 4);
            }
        }
        f32x4 acc0 = {0.f, 0.f, 0.f, 0.f};
        f32x4 acc1 = {0.f, 0.f, 0.f, 0.f};
#pragma unroll
        for (int ks = 0; ks < 4; ++ks) {
            float v[8];
            *(float4*)(v)     = buf[j & 1][2 * ks];
            *(float4*)(v + 4) = buf[j & 1][2 * ks + 1];
            unsigned p[4], q[4];
#pragma unroll
            for (int i = 0; i < 4; ++i) split2pk(v[2*i], v[2*i+1], p[i], q[i]);
            uint4 q1 = {p[0], p[1], p[2], p[3]};
            uint4 q2 = {q[0], q[1], q[2], q[3]};
            bf16x8 a1 = __builtin_bit_cast(bf16x8, q1);
            bf16x8 a2 = __builtin_bit_cast(bf16x8, q2);
            bf16x8 B10 = __builtin_bit_cast(bf16x8, *(const uint4*)(bfr + BOFF(0, ks, 0) + l * 4));
            bf16x8 B20 = __builtin_bit_cast(bf16x8, *(const uint4*)(bfr + BOFF(0, ks, 1) + l * 4));
            bf16x8 B11 = __builtin_bit_cast(bf16x8, *(const uint4*)(bfr + BOFF(1, ks, 0) + l * 4));
            bf16x8 B21 = __builtin_bit_cast(bf16x8, *(const uint4*)(bfr + BOFF(1, ks, 1) + l * 4));
            acc0 = __builtin_amdgcn_mfma_f32_16x16x32_bf16(a1, B10, acc0, 0, 0, 0);
            acc1 = __builtin_amdgcn_mfma_f32_16x16x32_bf16(a1, B11, acc1, 0, 0, 0);
            acc0 = __builtin_amdgcn_mfma_f32_16x16x32_bf16(a2, B10, acc0, 0, 0, 0);
            acc1 = __builtin_amdgcn_mfma_f32_16x16x32_bf16(a2, B11, acc1, 0, 0, 0);
            acc0 = __builtin_amdgcn_mfma_f32_16x16x32_bf16(a1, B20, acc0, 0, 0, 0);
            acc1 = __builtin_amdgcn_mfma_f32_16x16x32_bf16(a1, B21, acc1, 0, 0, 0);
        }
        // C/D layout: col = l&15, row-in-tile = (l>>4)*4 + reg -> wave-private Ct
        const int crow = j * 16 + (l >> 4) * 4;
        const int ccol = l & 15;
#pragma unroll
        for (int r = 0; r < 4; ++r) {
            myCt[(crow + r) * CSTRIDE + ccol]      = acc0[r];
            myCt[(crow + r) * CSTRIDE + 16 + ccol] = acc1[r];
        }
    }

    // in-wave handoff: DS ops complete in order per wave; compiler inserts the
    // lgkmcnt waits for the read results. No barrier needed (wave-private slice).
    float x[32];
#pragma unroll
    for (int c = 0; c < 8; ++c)
        *(float4*)(x + c * 4) = *(const float4*)(myCt + l * CSTRIDE + c * 4);

    // ---------------- tail: lane l owns row rows0 + l -------------------------
    float m = 0.f;
#pragma unroll
    for (int j = 0; j < 32; ++j) m += x[j];
    m *= (1.f / 32.f);
    float var = 0.f;
#pragma unroll
    for (int j = 0; j < 32; ++j) { const float d = x[j] - m; var = fmaf(d, d, var); }
    var *= (1.f / 32.f);
    const float rs1 = rsqrtf(var + 1e-5f);

    float z[32];
#pragma unroll
    for (int j = 0; j < 32; ++j) {
        float y = (x[j] - m) * rs1 * g1[j] + b1[j];
        z[j] = (y >= 0.f) ? y : 0.1f * y;
    }

    float a2v[16];
#pragma unroll
    for (int k = 0; k < 16; ++k) {
        const float* __restrict__ wrow = W2 + k * 32;
        float s = 0.f;
#pragma unroll
        for (int j = 0; j < 32; ++j) s = fmaf(z[j], wrow[j], s);
        a2v[k] = s;
    }

    float m2 = 0.f;
#pragma unroll
    for (int k = 0; k < 16; ++k) m2 += a2v[k];
    m2 *= (1.f / 16.f);
    float v2 = 0.f;
#pragma unroll
    for (int k = 0; k < 16; ++k) { const float d = a2v[k] - m2; v2 = fmaf(d, d, v2); }
    v2 *= (1.f / 16.f);
    const float rs2 = rsqrtf(v2 + 1e-5f);

    float z2[16];
#pragma unroll
    for (int k = 0; k < 16; ++k) {
        float y = (a2v[k] - m2) * rs2 * g2[k] + b2[k];
        z2[k] = (y >= 0.f) ? y : 0.1f * y;
    }

    float o[3];
#pragma unroll
    for (int q = 0; q < 3; ++q) {
        const float* __restrict__ wrow = W3 + q * 16;
        float s = b3[q];
#pragma unroll
        for (int k = 0; k < 16; ++k) s = fmaf(z2[k], wrow[k], s);
        o[q] = s;
    }
    const float nrm = sqrtf(o[0]*o[0] + o[1]*o[1] + o[2]*o[2]);
    const float inv = 1.f / fmaxf(nrm, 1e-12f);

    const size_t myrow = rows0 + l;
    if (myrow < (size_t)N) {
        out[myrow * 3 + 0] = o[0] * inv;
        out[myrow * 3 + 1] = o[1] * inv;
        out[myrow * 3 + 2] = o[2] * inv;
    }
}

extern "C" void kernel_launch(void* const* d_in, const int* in_sizes, int n_in,
                              void* d_out, int out_size, void* d_ws, size_t ws_size,
                              hipStream_t stream) {
    const float* feat = (const float*)d_in[0];
    const float* W1   = (const float*)d_in[1];
    const float* g1   = (const float*)d_in[2];
    const float* b1   = (const float*)d_in[3];
    const float* W2   = (const float*)d_in[4];
    const float* g2   = (const float*)d_in[5];
    const float* b2   = (const float*)d_in[6];
    const float* W3   = (const float*)d_in[7];
    const float* b3   = (const float*)d_in[8];
    float* out = (float*)d_out;

    const int N = in_sizes[0] / 128;
    const int grid = (N + 255) / 256;

    decoder_kernel<<<grid, TPB, 0, stream>>>(feat, W1, g1, b1, W2, g2, b2, W3, b3, out, N);
}

// Round 10
// 118.814 us; speedup vs baseline: 2.3688x; 1.0156x over previous
//
#include <hip/hip_runtime.h>
#include <math.h>

typedef short bf16x8 __attribute__((ext_vector_type(8)));   // 8 bf16 in 4 VGPRs
typedef float f32x4  __attribute__((ext_vector_type(4)));
typedef float f32x2  __attribute__((ext_vector_type(2)));   // -> v_pk_*_f32

#define TPB 256
#define CSTRIDE 36        // Ct row stride (floats): rows 16B-aligned
#define BFR_BYTES 16384   // 2 ntiles x 4 ksteps x 2 planes x 64 lanes x 16B
#define CT_BYTES (256 * CSTRIDE * 4)      // 4 waves x 64 rows
#define BOFF(nt, ks, p) ((((nt)*4 + (ks))*2 + (p))*256)

#define PKFMA(a, b, c) __builtin_elementwise_fma((a), (b), (c))

// v_cvt_pk_bf16_f32: RNE-round two f32 into one packed 2xbf16 word
__device__ __forceinline__ unsigned cvt_pk_bf16(float lo, float hi) {
    unsigned r;
    asm("v_cvt_pk_bf16_f32 %0, %1, %2" : "=v"(r) : "v"(lo), "v"(hi));
    return r;
}
// 2-plane split of a pair: p = RNE(x0,x1); q = RNE(residuals). pk_sub for residual.
__device__ __forceinline__ void split2pk(float x0, float x1, unsigned &p, unsigned &q) {
    p = cvt_pk_bf16(x0, x1);
    f32x2 xv = {x0, x1};
    f32x2 fv = {__uint_as_float(p << 16), __uint_as_float(p & 0xffff0000u)};
    f32x2 r = xv - fv;                    // v_pk_add_f32 (neg)
    q = cvt_pk_bf16(r.x, r.y);
}
// branchless leaky on a pair: max(y,0) + 0.1*min(y,0)
__device__ __forceinline__ f32x2 leaky2(f32x2 y) {
    const f32x2 zero = {0.f, 0.f};
    const f32x2 slope = {0.1f, 0.1f};
    return PKFMA(__builtin_elementwise_min(y, zero), slope,
                 __builtin_elementwise_max(y, zero));
}

__global__ __launch_bounds__(TPB, 3) void decoder_kernel(
    const float* __restrict__ feat,
    const float* __restrict__ W1, const float* __restrict__ g1, const float* __restrict__ b1,
    const float* __restrict__ W2, const float* __restrict__ g2, const float* __restrict__ b2,
    const float* __restrict__ W3, const float* __restrict__ b3,
    float* __restrict__ out, int N)
{
    __shared__ __align__(16) unsigned char lds[BFR_BYTES + CT_BYTES];  // 53248 B -> 3/CU
    unsigned* bfr = (unsigned*)lds;

    const int t = threadIdx.x;
    const int l = t & 63;
    const int w = t >> 6;
    const int arow = l & 15;        // A-fragment: m = l&15
    const int acol = (l >> 4) * 8;  //             k-base = (l>>4)*8
    float* myCt = (float*)(lds + BFR_BYTES) + w * 64 * CSTRIDE;  // wave-private slice

    const size_t rows0 = (size_t)blockIdx.x * 256 + (size_t)w * 64;  // this wave's rows

    // issue tile-0 loads FIRST; they fly under the prologue + barrier
    float4 buf[2][8];
    {
        size_t rr = rows0 + arow;
        if (rr >= (size_t)N) rr = N - 1;
        const float* ap = feat + rr * 128 + acol;
#pragma unroll
        for (int ks = 0; ks < 4; ++ks) {
            buf[0][2 * ks]     = *(const float4*)(ap + ks * 32);
            buf[0][2 * ks + 1] = *(const float4*)(ap + ks * 32 + 4);
        }
    }

    // ---------------- prologue: W1 -> 2-plane bf16 B-fragments in LDS --------
    for (int c = t; c < 512; c += 256) {
        const int lc = c & 63, ks = (c >> 6) & 3, nt = (c >> 8) & 1;
        const float* wp = W1 + (nt * 16 + (lc & 15)) * 128 + ks * 32 + (lc >> 4) * 8;
        float v[8];
        *(float4*)(v)     = *(const float4*)(wp);
        *(float4*)(v + 4) = *(const float4*)(wp + 4);
        unsigned p[4], q[4];
#pragma unroll
        for (int i = 0; i < 4; ++i) split2pk(v[2*i], v[2*i+1], p[i], q[i]);
        uint4 q1 = {p[0], p[1], p[2], p[3]};
        uint4 q2 = {q[0], q[1], q[2], q[3]};
        *(uint4*)(bfr + BOFF(nt, ks, 0) + lc * 4) = q1;
        *(uint4*)(bfr + BOFF(nt, ks, 1) + lc * 4) = q2;
    }
    __syncthreads();   // the ONLY barrier; bfr read-only hereafter, waves free-run

    // ---------------- layer 1 via MFMA: 4 row-tiles of 16, wave-private ------
#pragma unroll
    for (int j = 0; j < 4; ++j) {
        if (j < 3) {   // prefetch next row-tile
            size_t rr = rows0 + (j + 1) * 16 + arow;
            if (rr >= (size_t)N) rr = N - 1;
            const float* ap = feat + rr * 128 + acol;
#pragma unroll
            for (int ks = 0; ks < 4; ++ks) {
                buf[(j + 1) & 1][2 * ks]     = *(const float4*)(ap + ks * 32);
                buf[(j + 1) & 1][2 * ks + 1] = *(const float4*)(ap + ks * 32 + 4);
            }
        }
        f32x4 acc0 = {0.f, 0.f, 0.f, 0.f};
        f32x4 acc1 = {0.f, 0.f, 0.f, 0.f};
#pragma unroll
        for (int ks = 0; ks < 4; ++ks) {
            float v[8];
            *(float4*)(v)     = buf[j & 1][2 * ks];
            *(float4*)(v + 4) = buf[j & 1][2 * ks + 1];
            unsigned p[4], q[4];
#pragma unroll
            for (int i = 0; i < 4; ++i) split2pk(v[2*i], v[2*i+1], p[i], q[i]);
            uint4 q1 = {p[0], p[1], p[2], p[3]};
            uint4 q2 = {q[0], q[1], q[2], q[3]};
            bf16x8 a1 = __builtin_bit_cast(bf16x8, q1);
            bf16x8 a2 = __builtin_bit_cast(bf16x8, q2);
            bf16x8 B10 = __builtin_bit_cast(bf16x8, *(const uint4*)(bfr + BOFF(0, ks, 0) + l * 4));
            bf16x8 B20 = __builtin_bit_cast(bf16x8, *(const uint4*)(bfr + BOFF(0, ks, 1) + l * 4));
            bf16x8 B11 = __builtin_bit_cast(bf16x8, *(const uint4*)(bfr + BOFF(1, ks, 0) + l * 4));
            bf16x8 B21 = __builtin_bit_cast(bf16x8, *(const uint4*)(bfr + BOFF(1, ks, 1) + l * 4));
            acc0 = __builtin_amdgcn_mfma_f32_16x16x32_bf16(a1, B10, acc0, 0, 0, 0);
            acc1 = __builtin_amdgcn_mfma_f32_16x16x32_bf16(a1, B11, acc1, 0, 0, 0);
            acc0 = __builtin_amdgcn_mfma_f32_16x16x32_bf16(a2, B10, acc0, 0, 0, 0);
            acc1 = __builtin_amdgcn_mfma_f32_16x16x32_bf16(a2, B11, acc1, 0, 0, 0);
            acc0 = __builtin_amdgcn_mfma_f32_16x16x32_bf16(a1, B20, acc0, 0, 0, 0);
            acc1 = __builtin_amdgcn_mfma_f32_16x16x32_bf16(a1, B21, acc1, 0, 0, 0);
        }
        // C/D layout: col = l&15, row-in-tile = (l>>4)*4 + reg -> wave-private Ct
        const int crow = j * 16 + (l >> 4) * 4;
        const int ccol = l & 15;
#pragma unroll
        for (int r = 0; r < 4; ++r) {
            myCt[(crow + r) * CSTRIDE + ccol]      = acc0[r];
            myCt[(crow + r) * CSTRIDE + 16 + ccol] = acc1[r];
        }
    }

    // in-wave handoff: DS ops complete in order per wave; no barrier needed.
    f32x2 xp[16];
#pragma unroll
    for (int c = 0; c < 8; ++c) {
        const float4 v = *(const float4*)(myCt + l * CSTRIDE + c * 4);
        xp[2 * c]     = f32x2{v.x, v.y};
        xp[2 * c + 1] = f32x2{v.z, v.w};
    }

    // ---------------- tail (packed f32x2): lane l owns row rows0 + l ----------
    f32x2 sv = xp[0];
#pragma unroll
    for (int i = 1; i < 16; ++i) sv += xp[i];
    const float m = (sv.x + sv.y) * (1.f / 32.f);
    const f32x2 mv = {m, m};
    f32x2 vv = {0.f, 0.f};
#pragma unroll
    for (int i = 0; i < 16; ++i) { const f32x2 d = xp[i] - mv; vv = PKFMA(d, d, vv); }
    const float rs1 = rsqrtf((vv.x + vv.y) * (1.f / 32.f) + 1e-5f);
    const f32x2 rs1v = {rs1, rs1};

    f32x2 zp[16];
#pragma unroll
    for (int i = 0; i < 16; ++i) {
        const f32x2 gb = *(const f32x2*)(g1 + 2 * i);
        const f32x2 bb = *(const f32x2*)(b1 + 2 * i);
        zp[i] = leaky2(PKFMA((xp[i] - mv) * rs1v, gb, bb));
    }

    // layer 2: pk-FMA along the reduce dim; weights contiguous -> s_load pairs
    float a2v[16];
#pragma unroll
    for (int k = 0; k < 16; ++k) {
        const float* __restrict__ wrow = W2 + k * 32;
        f32x2 acc = {0.f, 0.f};
#pragma unroll
        for (int jj = 0; jj < 16; ++jj)
            acc = PKFMA(zp[jj], *(const f32x2*)(wrow + 2 * jj), acc);
        a2v[k] = acc.x + acc.y;
    }

    f32x2 a2p[8];
#pragma unroll
    for (int i = 0; i < 8; ++i) a2p[i] = f32x2{a2v[2 * i], a2v[2 * i + 1]};

    f32x2 s2 = a2p[0];
#pragma unroll
    for (int i = 1; i < 8; ++i) s2 += a2p[i];
    const float m2 = (s2.x + s2.y) * (1.f / 16.f);
    const f32x2 m2v = {m2, m2};
    f32x2 v2v = {0.f, 0.f};
#pragma unroll
    for (int i = 0; i < 8; ++i) { const f32x2 d = a2p[i] - m2v; v2v = PKFMA(d, d, v2v); }
    const float rs2 = rsqrtf((v2v.x + v2v.y) * (1.f / 16.f) + 1e-5f);
    const f32x2 rs2v = {rs2, rs2};

    f32x2 z2p[8];
#pragma unroll
    for (int i = 0; i < 8; ++i) {
        const f32x2 gb = *(const f32x2*)(g2 + 2 * i);
        const f32x2 bb = *(const f32x2*)(b2 + 2 * i);
        z2p[i] = leaky2(PKFMA((a2p[i] - m2v) * rs2v, gb, bb));
    }

    float o[3];
#pragma unroll
    for (int q = 0; q < 3; ++q) {
        const float* __restrict__ wrow = W3 + q * 16;
        f32x2 acc = {0.f, 0.f};
#pragma unroll
        for (int jj = 0; jj < 8; ++jj)
            acc = PKFMA(z2p[jj], *(const f32x2*)(wrow + 2 * jj), acc);
        o[q] = b3[q] + acc.x + acc.y;
    }
    const float nrm = sqrtf(o[0]*o[0] + o[1]*o[1] + o[2]*o[2]);
    const float inv = 1.f / fmaxf(nrm, 1e-12f);

    const size_t myrow = rows0 + l;
    if (myrow < (size_t)N) {
        out[myrow * 3 + 0] = o[0] * inv;
        out[myrow * 3 + 1] = o[1] * inv;
        out[myrow * 3 + 2] = o[2] * inv;
    }
}

extern "C" void kernel_launch(void* const* d_in, const int* in_sizes, int n_in,
                              void* d_out, int out_size, void* d_ws, size_t ws_size,
                              hipStream_t stream) {
    const float* feat = (const float*)d_in[0];
    const float* W1   = (const float*)d_in[1];
    const float* g1   = (const float*)d_in[2];
    const float* b1   = (const float*)d_in[3];
    const float* W2   = (const float*)d_in[4];
    const float* g2   = (const float*)d_in[5];
    const float* b2   = (const float*)d_in[6];
    const float* W3   = (const float*)d_in[7];
    const float* b3   = (const float*)d_in[8];
    float* out = (float*)d_out;

    const int N = in_sizes[0] / 128;
    const int grid = (N + 255) / 256;

    decoder_kernel<<<grid, TPB, 0, stream>>>(feat, W1, g1, b1, W2, g2, b2, W3, b3, out, N);
}

// Round 11
// 112.721 us; speedup vs baseline: 2.4968x; 1.0541x over previous
//
#include <hip/hip_runtime.h>
#include <math.h>

typedef short bf16x8 __attribute__((ext_vector_type(8)));   // 8 bf16 in 4 VGPRs
typedef float f32x4  __attribute__((ext_vector_type(4)));
typedef float f32x2  __attribute__((ext_vector_type(2)));   // -> v_pk_*_f32

#define TPB 256
#define GRID 768          // persistent: 3 blocks/CU, 12 waves/CU, stride 3072 chunks
#define CSTRIDE 36        // Ct row stride (floats): rows 16B-aligned
#define BFR_BYTES 16384   // 2 ntiles x 4 ksteps x 2 planes x 64 lanes x 16B
#define CT_BYTES (256 * CSTRIDE * 4)      // 4 waves x 64 rows
#define BOFF(nt, ks, p) ((((nt)*4 + (ks))*2 + (p))*256)

#define PKFMA(a, b, c) __builtin_elementwise_fma((a), (b), (c))

// v_cvt_pk_bf16_f32: RNE-round two f32 into one packed 2xbf16 word
__device__ __forceinline__ unsigned cvt_pk_bf16(float lo, float hi) {
    unsigned r;
    asm("v_cvt_pk_bf16_f32 %0, %1, %2" : "=v"(r) : "v"(lo), "v"(hi));
    return r;
}
// 2-plane split of a pair: p = RNE(x0,x1); q = RNE(residuals)
__device__ __forceinline__ void split2pk(float x0, float x1, unsigned &p, unsigned &q) {
    p = cvt_pk_bf16(x0, x1);
    f32x2 xv = {x0, x1};
    f32x2 fv = {__uint_as_float(p << 16), __uint_as_float(p & 0xffff0000u)};
    f32x2 r = xv - fv;
    q = cvt_pk_bf16(r.x, r.y);
}
// branchless leaky on a pair: max(y,0) + 0.1*min(y,0)
__device__ __forceinline__ f32x2 leaky2(f32x2 y) {
    const f32x2 zero = {0.f, 0.f};
    const f32x2 slope = {0.1f, 0.1f};
    return PKFMA(__builtin_elementwise_min(y, zero), slope,
                 __builtin_elementwise_max(y, zero));
}

// load one 16-row A-tile (rows rbase..rbase+15, this lane's fragment slice)
__device__ __forceinline__ void load_tile(float4* dst, const float* __restrict__ feat,
                                          unsigned rbase, int arow, int acol, unsigned nm1) {
    unsigned rr = rbase + arow;
    rr = rr < nm1 ? rr : nm1;                    // v_min_u32
    const float* ap = feat + (size_t)rr * 128 + acol;
#pragma unroll
    for (int ks = 0; ks < 4; ++ks) {
        dst[2 * ks]     = *(const float4*)(ap + ks * 32);
        dst[2 * ks + 1] = *(const float4*)(ap + ks * 32 + 4);
    }
}

__global__ __launch_bounds__(TPB, 3) void decoder_kernel(
    const float* __restrict__ feat,
    const float* __restrict__ W1, const float* __restrict__ g1, const float* __restrict__ b1,
    const float* __restrict__ W2, const float* __restrict__ g2, const float* __restrict__ b2,
    const float* __restrict__ W3, const float* __restrict__ b3,
    float* __restrict__ out, int N, unsigned nchunks)
{
    __shared__ __align__(16) unsigned char lds[BFR_BYTES + CT_BYTES];  // 53248 B -> 3/CU
    unsigned* bfr = (unsigned*)lds;

    const int t = threadIdx.x;
    const int l = t & 63;
    const int w = t >> 6;
    const int arow = l & 15;        // A-fragment: m = l&15
    const int acol = (l >> 4) * 8;  //             k-base = (l>>4)*8
    const unsigned nm1 = (unsigned)(N - 1);
    float* myCt = (float*)(lds + BFR_BYTES) + w * 64 * CSTRIDE;  // wave-private slice

    const unsigned wid = blockIdx.x * 4 + w;   // global wave id, 0..3071
    const unsigned NW  = GRID * 4;             // chunk stride between my chunks

    // issue tile-0 loads of my FIRST chunk before the prologue; they fly under it
    float4 buf[2][8];
    unsigned c = wid;
    if (c < nchunks) load_tile(buf[0], feat, c * 64, arow, acol, nm1);

    // ---------------- prologue (once): W1 -> 2-plane bf16 B-fragments --------
    for (int cc = t; cc < 512; cc += 256) {
        const int lc = cc & 63, ks = (cc >> 6) & 3, nt = (cc >> 8) & 1;
        const float* wp = W1 + (nt * 16 + (lc & 15)) * 128 + ks * 32 + (lc >> 4) * 8;
        float v[8];
        *(float4*)(v)     = *(const float4*)(wp);
        *(float4*)(v + 4) = *(const float4*)(wp + 4);
        unsigned p[4], q[4];
#pragma unroll
        for (int i = 0; i < 4; ++i) split2pk(v[2*i], v[2*i+1], p[i], q[i]);
        uint4 q1 = {p[0], p[1], p[2], p[3]};
        uint4 q2 = {q[0], q[1], q[2], q[3]};
        *(uint4*)(bfr + BOFF(nt, ks, 0) + lc * 4) = q1;
        *(uint4*)(bfr + BOFF(nt, ks, 1) + lc * 4) = q2;
    }
    __syncthreads();   // the ONLY barrier; bfr read-only hereafter, waves free-run

    // ---------------- persistent per-wave chunk loop --------------------------
    for (; c < nchunks; c += NW) {
        const unsigned base = c * 64;

#pragma unroll
        for (int j = 0; j < 4; ++j) {
            // prefetch: j<3 -> next tile of this chunk; j==3 -> tile 0 of my NEXT chunk
            if (j < 3) {
                load_tile(buf[(j + 1) & 1], feat, base + (j + 1) * 16, arow, acol, nm1);
            } else {
                const unsigned cn = c + NW;
                if (cn < nchunks)
                    load_tile(buf[0], feat, cn * 64, arow, acol, nm1);
            }
            f32x4 acc0 = {0.f, 0.f, 0.f, 0.f};
            f32x4 acc1 = {0.f, 0.f, 0.f, 0.f};
#pragma unroll
            for (int ks = 0; ks < 4; ++ks) {
                float v[8];
                *(float4*)(v)     = buf[j & 1][2 * ks];
                *(float4*)(v + 4) = buf[j & 1][2 * ks + 1];
                unsigned p[4], q[4];
#pragma unroll
                for (int i = 0; i < 4; ++i) split2pk(v[2*i], v[2*i+1], p[i], q[i]);
                uint4 q1 = {p[0], p[1], p[2], p[3]};
                uint4 q2 = {q[0], q[1], q[2], q[3]};
                bf16x8 a1 = __builtin_bit_cast(bf16x8, q1);
                bf16x8 a2 = __builtin_bit_cast(bf16x8, q2);
                bf16x8 B10 = __builtin_bit_cast(bf16x8, *(const uint4*)(bfr + BOFF(0, ks, 0) + l * 4));
                bf16x8 B20 = __builtin_bit_cast(bf16x8, *(const uint4*)(bfr + BOFF(0, ks, 1) + l * 4));
                bf16x8 B11 = __builtin_bit_cast(bf16x8, *(const uint4*)(bfr + BOFF(1, ks, 0) + l * 4));
                bf16x8 B21 = __builtin_bit_cast(bf16x8, *(const uint4*)(bfr + BOFF(1, ks, 1) + l * 4));
                acc0 = __builtin_amdgcn_mfma_f32_16x16x32_bf16(a1, B10, acc0, 0, 0, 0);
                acc1 = __builtin_amdgcn_mfma_f32_16x16x32_bf16(a1, B11, acc1, 0, 0, 0);
                acc0 = __builtin_amdgcn_mfma_f32_16x16x32_bf16(a2, B10, acc0, 0, 0, 0);
                acc1 = __builtin_amdgcn_mfma_f32_16x16x32_bf16(a2, B11, acc1, 0, 0, 0);
                acc0 = __builtin_amdgcn_mfma_f32_16x16x32_bf16(a1, B20, acc0, 0, 0, 0);
                acc1 = __builtin_amdgcn_mfma_f32_16x16x32_bf16(a1, B21, acc1, 0, 0, 0);
            }
            // C/D layout: col = l&15, row-in-tile = (l>>4)*4 + reg -> wave-private Ct
            const int crow = j * 16 + (l >> 4) * 4;
            const int ccol = l & 15;
#pragma unroll
            for (int r = 0; r < 4; ++r) {
                myCt[(crow + r) * CSTRIDE + ccol]      = acc0[r];
                myCt[(crow + r) * CSTRIDE + 16 + ccol] = acc1[r];
            }
        }

        // in-wave handoff: DS ops complete in order per wave; no barrier needed.
        // Next chunk's tile-0 loads stay in flight through the whole tail.
        f32x2 xp[16];
#pragma unroll
        for (int cc = 0; cc < 8; ++cc) {
            const float4 v = *(const float4*)(myCt + l * CSTRIDE + cc * 4);
            xp[2 * cc]     = f32x2{v.x, v.y};
            xp[2 * cc + 1] = f32x2{v.z, v.w};
        }

        // ---------------- tail (packed f32x2): lane l owns row base + l -------
        f32x2 sv = xp[0];
#pragma unroll
        for (int i = 1; i < 16; ++i) sv += xp[i];
        const float m = (sv.x + sv.y) * (1.f / 32.f);
        const f32x2 mv = {m, m};
        f32x2 vv = {0.f, 0.f};
#pragma unroll
        for (int i = 0; i < 16; ++i) { const f32x2 d = xp[i] - mv; vv = PKFMA(d, d, vv); }
        const float rs1 = rsqrtf((vv.x + vv.y) * (1.f / 32.f) + 1e-5f);
        const f32x2 rs1v = {rs1, rs1};

        f32x2 zp[16];
#pragma unroll
        for (int i = 0; i < 16; ++i) {
            const f32x2 gb = *(const f32x2*)(g1 + 2 * i);
            const f32x2 bb = *(const f32x2*)(b1 + 2 * i);
            zp[i] = leaky2(PKFMA((xp[i] - mv) * rs1v, gb, bb));
        }

        float a2v[16];
#pragma unroll
        for (int k = 0; k < 16; ++k) {
            const float* __restrict__ wrow = W2 + k * 32;
            f32x2 acc = {0.f, 0.f};
#pragma unroll
            for (int jj = 0; jj < 16; ++jj)
                acc = PKFMA(zp[jj], *(const f32x2*)(wrow + 2 * jj), acc);
            a2v[k] = acc.x + acc.y;
        }

        f32x2 a2p[8];
#pragma unroll
        for (int i = 0; i < 8; ++i) a2p[i] = f32x2{a2v[2 * i], a2v[2 * i + 1]};

        f32x2 s2 = a2p[0];
#pragma unroll
        for (int i = 1; i < 8; ++i) s2 += a2p[i];
        const float m2 = (s2.x + s2.y) * (1.f / 16.f);
        const f32x2 m2v = {m2, m2};
        f32x2 v2v = {0.f, 0.f};
#pragma unroll
        for (int i = 0; i < 8; ++i) { const f32x2 d = a2p[i] - m2v; v2v = PKFMA(d, d, v2v); }
        const float rs2 = rsqrtf((v2v.x + v2v.y) * (1.f / 16.f) + 1e-5f);
        const f32x2 rs2v = {rs2, rs2};

        f32x2 z2p[8];
#pragma unroll
        for (int i = 0; i < 8; ++i) {
            const f32x2 gb = *(const f32x2*)(g2 + 2 * i);
            const f32x2 bb = *(const f32x2*)(b2 + 2 * i);
            z2p[i] = leaky2(PKFMA((a2p[i] - m2v) * rs2v, gb, bb));
        }

        float o[3];
#pragma unroll
        for (int q = 0; q < 3; ++q) {
            const float* __restrict__ wrow = W3 + q * 16;
            f32x2 acc = {0.f, 0.f};
#pragma unroll
            for (int jj = 0; jj < 8; ++jj)
                acc = PKFMA(z2p[jj], *(const f32x2*)(wrow + 2 * jj), acc);
            o[q] = b3[q] + acc.x + acc.y;
        }
        const float nrm = sqrtf(o[0]*o[0] + o[1]*o[1] + o[2]*o[2]);
        const float inv = 1.f / fmaxf(nrm, 1e-12f);

        const size_t myrow = (size_t)base + l;
        if (myrow < (size_t)N) {
            out[myrow * 3 + 0] = o[0] * inv;
            out[myrow * 3 + 1] = o[1] * inv;
            out[myrow * 3 + 2] = o[2] * inv;
        }
    }
}

extern "C" void kernel_launch(void* const* d_in, const int* in_sizes, int n_in,
                              void* d_out, int out_size, void* d_ws, size_t ws_size,
                              hipStream_t stream) {
    const float* feat = (const float*)d_in[0];
    const float* W1   = (const float*)d_in[1];
    const float* g1   = (const float*)d_in[2];
    const float* b1   = (const float*)d_in[3];
    const float* W2   = (const float*)d_in[4];
    const float* g2   = (const float*)d_in[5];
    const float* b2   = (const float*)d_in[6];
    const float* W3   = (const float*)d_in[7];
    const float* b3   = (const float*)d_in[8];
    float* out = (float*)d_out;

    const int N = in_sizes[0] / 128;
    const unsigned nchunks = (unsigned)((N + 63) / 64);

    decoder_kernel<<<GRID, TPB, 0, stream>>>(feat, W1, g1, b1, W2, g2, b2, W3, b3,
                                             out, N, nchunks);
}